// Round 2
// baseline (280.630 us; speedup 1.0000x reference)
//
#include <hip/hip_runtime.h>
#include <math.h>

#define B_ 4
#define N_ 33600
#define G_ 100
#define NCLS 80
#define STRIDE 85   // 4 box + 80 cls + 1 obj
#define TK 10
#define OBJ_BLOCKS 2048

__device__ __forceinline__ float sigmoidf_(float x) {
    return 1.0f / (1.0f + expf(-x));
}
__device__ __forceinline__ float softplusf_(float x) {
    return fmaxf(x, 0.0f) + log1pf(expf(-fabsf(x)));
}
__device__ __forceinline__ float waveRedSum(float v) {
    #pragma unroll
    for (int off = 32; off; off >>= 1) v += __shfl_xor(v, off, 64);
    return v;
}

// ---------------------------------------------------------------- stage 1
// candidate mask + (fused) per-candidate spsum = sum_c softplus(sigmoid(cls))
__global__ void k_cand(const float* __restrict__ gtb,
                       const float* __restrict__ anc,
                       const float* __restrict__ pred,
                       unsigned char* __restrict__ mask,
                       float* __restrict__ spsum)
{
    __shared__ float gx[G_], gy[G_];
    const int b = blockIdx.y;
    const int tid = threadIdx.x;
    if (tid < G_) {
        gx[tid] = gtb[(b * G_ + tid) * 4 + 0];
        gy[tid] = gtb[(b * G_ + tid) * 4 + 1];
    }
    __syncthreads();
    const int n = blockIdx.x * blockDim.x + tid;
    if (n >= N_) return;
    const float ax = anc[n * 2 + 0], ay = anc[n * 2 + 1];
    unsigned char c = 0;
    for (int g = 0; g < G_; ++g) {
        const float dx = ax - gx[g], dy = ay - gy[g];
        if (dx * dx + dy * dy < 6.25f) { c = 1; break; }
    }
    mask[b * N_ + n] = c;
    if (c) {
        const float* row = pred + (size_t)(b * N_ + n) * STRIDE + 4;
        float s = 0.0f;
        for (int cc = 0; cc < NCLS; ++cc) {
            s += softplusf_(sigmoidf_(row[cc]));
        }
        spsum[b * N_ + n] = s;
    }
}

// ---------------------------------------------------------------- stage 2
// ordered compaction of candidate indices; one block per image
__global__ void k_compact(const unsigned char* __restrict__ mask,
                          int* __restrict__ cidx,
                          int* __restrict__ counts) // [b][0]=n_cand, [b][1]=all_cand
{
    const int b = blockIdx.x;
    const int tid = threadIdx.x;
    const int lane = tid & 63, wid = tid >> 6;
    __shared__ int wsum[4];
    int base = 0;
    const int CH = 1024; // 256 threads * 4 bytes
    for (int chunk = 0; chunk * CH < N_; ++chunk) {
        const int i0 = chunk * CH + tid * 4;
        unsigned m0 = 0, m1 = 0, m2 = 0, m3 = 0;
        if (i0 + 3 < N_) {  // N_ % 4 == 0, so in-range is all-or-nothing
            const uchar4 v = *reinterpret_cast<const uchar4*>(&mask[b * N_ + i0]);
            m0 = v.x; m1 = v.y; m2 = v.z; m3 = v.w;
        }
        int cnt = (int)(m0 + m1 + m2 + m3);
        int incl = cnt;
        #pragma unroll
        for (int off = 1; off < 64; off <<= 1) {
            const int v = __shfl_up(incl, off, 64);
            if (lane >= off) incl += v;
        }
        if (lane == 63) wsum[wid] = incl;
        __syncthreads();
        int wbase = 0;
        for (int w = 0; w < wid; ++w) wbase += wsum[w];
        const int ctot = wsum[0] + wsum[1] + wsum[2] + wsum[3];
        int pos = base + wbase + (incl - cnt);
        if (m0) cidx[b * N_ + pos++] = i0 + 0;
        if (m1) cidx[b * N_ + pos++] = i0 + 1;
        if (m2) cidx[b * N_ + pos++] = i0 + 2;
        if (m3) cidx[b * N_ + pos++] = i0 + 3;
        base += ctot;
        __syncthreads();
    }
    if (tid == 0) {
        counts[b * 2 + 0] = base;
        counts[b * 2 + 1] = (base == 0) ? 1 : 0; // fallback: all anchors candidates
    }
}

// ---------------------------------------------------------------- stage 3
// one wave per (b,g): iou col-sum -> dyn_k; stable top-10 smallest cost;
// scatter atomicMin((cost_bits<<32)|g) per kept anchor.
__global__ void __launch_bounds__(64)
k_topk(const float* __restrict__ pred,
       const float* __restrict__ gtb,
       const int* __restrict__ gtc,
       const int* __restrict__ cidx,
       const int* __restrict__ counts,
       const float* __restrict__ spsum,
       unsigned long long* __restrict__ bkey)
{
    const int b = blockIdx.y, g = blockIdx.x;
    const int lane = threadIdx.x;
    const int cnt = counts[b * 2 + 0];
    const int allc = counts[b * 2 + 1];
    const int count = allc ? N_ : cnt;

    const float* gb = gtb + (b * G_ + g) * 4;
    const float gxc = gb[0], gyc = gb[1], gw = gb[2], gh = gb[3];
    const float gx1 = gxc - gw * 0.5f, gy1 = gyc - gh * 0.5f;
    const float gx2 = gxc + gw * 0.5f, gy2 = gyc + gh * 0.5f;
    const float garea = gw * gh;
    const int cls = gtc[b * G_ + g];

    float kcost[TK];
    int   kslot[TK];
    #pragma unroll
    for (int j = 0; j < TK; ++j) { kcost[j] = INFINITY; kslot[j] = 0x7FFFFFFF; }

    float iousum = 0.0f;
    for (int i = lane; i < count; i += 64) {
        const int n = allc ? i : cidx[b * N_ + i];
        const float* pr = pred + (size_t)(b * N_ + n) * STRIDE;
        const float px = pr[0], py = pr[1], pw = pr[2], ph = pr[3];
        const float x1 = px - pw * 0.5f, y1 = py - ph * 0.5f;
        const float x2 = px + pw * 0.5f, y2 = py + ph * 0.5f;
        const float iw = fmaxf(fminf(x2, gx2) - fmaxf(x1, gx1), 0.0f);
        const float ih = fmaxf(fminf(y2, gy2) - fmaxf(y1, gy1), 0.0f);
        const float inter = iw * ih;
        const float uni = pw * ph + garea - inter + 1e-7f;
        const float iou = inter / uni;
        iousum += iou;
        const float sgc = sigmoidf_(pr[4 + cls]);
        float sp;
        if (allc) { // never taken in practice (no-candidate fallback)
            float s = 0.0f;
            for (int cc = 0; cc < NCLS; ++cc) s += softplusf_(sigmoidf_(pr[4 + cc]));
            sp = s;
        } else {
            sp = spsum[b * N_ + n];
        }
        float c = -logf(iou + 1e-8f) + 3.0f * (sp - sgc);
        int   s = i;
        // bubble-insert; slots within a lane strictly increase, so strict <
        // preserves lexicographic (cost, slot) order.
        #pragma unroll
        for (int j = 0; j < TK; ++j) {
            const bool lt = (c < kcost[j]);
            const float tc = kcost[j]; const int ts = kslot[j];
            if (lt) { kcost[j] = c; kslot[j] = s; c = tc; s = ts; }
        }
    }

    // wave-sum of iou column
    #pragma unroll
    for (int off = 32; off; off >>= 1) iousum += __shfl_xor(iousum, off, 64);

    // 10 rounds of wave-wide extract-min on packed (cost_bits, slot) keys.
    // cost > 0 always (cls_cost >= ~54), so float bits are order-preserving.
    unsigned long long win[TK];
    #pragma unroll
    for (int r = 0; r < TK; ++r) {
        const unsigned long long mykey =
            ((unsigned long long)__float_as_uint(kcost[0]) << 32) | (unsigned)kslot[0];
        unsigned long long k2 = mykey;
        #pragma unroll
        for (int off = 32; off; off >>= 1) {
            const unsigned long long o = __shfl_xor(k2, off, 64);
            k2 = (o < k2) ? o : k2;
        }
        win[r] = k2;
        if (mykey == k2) { // unique (slot unique per lane); pop my head
            #pragma unroll
            for (int j = 0; j < TK - 1; ++j) { kcost[j] = kcost[j + 1]; kslot[j] = kslot[j + 1]; }
            kcost[TK - 1] = INFINITY; kslot[TK - 1] = 0x7FFFFFFF;
        }
    }

    const int kmax = (count < TK) ? count : TK;
    int dk = (int)floorf(iousum);
    if (dk < 1) dk = 1;
    if (dk > kmax) dk = kmax;

    if (lane == 0) {
        #pragma unroll
        for (int r = 0; r < TK; ++r) {
            if (r < dk) {
                const unsigned slot = (unsigned)(win[r] & 0xFFFFFFFFull);
                const int n = allc ? (int)slot : cidx[b * N_ + (int)slot];
                const unsigned cbits = (unsigned)(win[r] >> 32);
                const unsigned long long key =
                    ((unsigned long long)cbits << 32) | (unsigned)g;
                atomicMin(&bkey[(size_t)b * N_ + n], key);
            }
        }
    }
}

// ---------------------------------------------------------------- stage 4
// coalesced streaming pass over ALL of pred: sum softplus(obj_logit).
// obj logit lives at flat column 84 of each 85-wide row; a float4 at flat
// index i contains it iff (4i)%85 in {81,82,83,84}.
__global__ void k_obj(const float* __restrict__ pred,
                      float* __restrict__ pobj)
{
    const float4* p4 = (const float4*)pred;
    const unsigned T = (unsigned)(B_ * N_ * STRIDE / 4); // 2,856,000 exactly
    float s = 0.0f;
    for (unsigned i = blockIdx.x * blockDim.x + threadIdx.x; i < T;
         i += gridDim.x * blockDim.x) {
        const float4 v = p4[i];
        const unsigned c0 = (i * 4u) % 85u;
        if (c0 >= 81u) {
            const float x = (c0 == 84u) ? v.x
                          : (c0 == 83u) ? v.y
                          : (c0 == 82u) ? v.z : v.w;
            s += softplusf_(x);
        }
    }
    s = waveRedSum(s);
    __shared__ float wsum[4];
    const int lane = threadIdx.x & 63, wid = threadIdx.x >> 6;
    if (lane == 0) wsum[wid] = s;
    __syncthreads();
    if (threadIdx.x == 0)
        pobj[blockIdx.x] = wsum[0] + wsum[1] + wsum[2] + wsum[3];
}

// ---------------------------------------------------------------- stage 5
// fg-only terms: box CIoU, focal cls, npos, and sum of fg obj logits (posum,
// subtracted from the streamed softplus sum in the final reduction).
__global__ void k_fg(const float* __restrict__ pred,
                     const float* __restrict__ gtb,
                     const int* __restrict__ gtc,
                     const unsigned long long* __restrict__ bkey,
                     float* __restrict__ pfg)
{
    const int b = blockIdx.y;
    const int tid = threadIdx.x;
    const int n = blockIdx.x * blockDim.x + tid;
    float posum = 0.0f, box = 0.0f, cls = 0.0f, npos = 0.0f;
    if (n < N_) {
        const unsigned long long key = bkey[(size_t)b * N_ + n];
        if (key != 0xFFFFFFFFFFFFFFFFull) {
            npos = 1.0f;
            const float* pr = pred + (size_t)(b * N_ + n) * STRIDE;
            posum = pr[STRIDE - 1];
            const int mg = (int)(unsigned)(key & 0xFFFFFFFFull);
            const float* gb = gtb + (b * G_ + mg) * 4;
            const float px = pr[0], py = pr[1], pw = pr[2], ph = pr[3];
            const float gx = gb[0], gy = gb[1], gw = gb[2], gh = gb[3];
            const float x11 = px - pw * 0.5f, y11 = py - ph * 0.5f;
            const float x12 = px + pw * 0.5f, y12 = py + ph * 0.5f;
            const float x21 = gx - gw * 0.5f, y21 = gy - gh * 0.5f;
            const float x22 = gx + gw * 0.5f, y22 = gy + gh * 0.5f;
            const float iw = fmaxf(fminf(x12, x22) - fmaxf(x11, x21), 0.0f);
            const float ih = fmaxf(fminf(y12, y22) - fmaxf(y11, y21), 0.0f);
            const float inter = iw * ih;
            const float uni = pw * ph + gw * gh - inter + 1e-7f;
            const float iou = inter / uni;
            const float cw = fmaxf(x12, x22) - fminf(x11, x21);
            const float chh = fmaxf(y12, y22) - fminf(y11, y21);
            const float c2 = cw * cw + chh * chh + 1e-7f;
            const float ddx = x11 + x12 - x21 - x22;
            const float ddy = y11 + y12 - y21 - y22;
            const float rho2 = (ddx * ddx + ddy * ddy) * 0.25f;
            const float dv = atanf(gw / (gh + 1e-7f)) - atanf(pw / (ph + 1e-7f));
            const float v = (float)(4.0 / (M_PI * M_PI)) * dv * dv;
            const float alpha = v / (v - iou + 1.0f + 1e-7f);
            const float ciou = iou - (rho2 / c2 + v * alpha);
            box = 1.0f - ciou;
            const int cg = gtc[b * G_ + mg];
            float csum = 0.0f;
            for (int c = 0; c < NCLS; ++c) {
                const float x = pr[4 + c];
                const float t = (c == cg) ? 1.0f : 0.0f;
                const float bce = softplusf_(x) - x * t;
                const float p = sigmoidf_(x);
                const float pt = (c == cg) ? p : (1.0f - p);
                const float om = 1.0f - pt;
                csum += 0.25f * om * om * bce;
            }
            cls = csum;
        }
    }
    posum = waveRedSum(posum);
    box = waveRedSum(box);
    cls = waveRedSum(cls);
    npos = waveRedSum(npos);
    __shared__ float wsum[4][4];
    const int lane = tid & 63, wid = tid >> 6;
    if (lane == 0) {
        wsum[wid][0] = posum; wsum[wid][1] = box;
        wsum[wid][2] = cls;   wsum[wid][3] = npos;
    }
    __syncthreads();
    if (tid == 0) {
        const int bid = blockIdx.y * gridDim.x + blockIdx.x;
        ((float4*)pfg)[bid] = make_float4(
            wsum[0][0] + wsum[1][0] + wsum[2][0] + wsum[3][0],
            wsum[0][1] + wsum[1][1] + wsum[2][1] + wsum[3][1],
            wsum[0][2] + wsum[1][2] + wsum[2][2] + wsum[3][2],
            wsum[0][3] + wsum[1][3] + wsum[2][3] + wsum[3][3]);
    }
}

// ---------------------------------------------------------------- stage 6
__global__ void k_final(const float* __restrict__ pobj, int nobj,
                        const float* __restrict__ pfg, int nfg,
                        float* __restrict__ out)
{
    const int tid = threadIdx.x;
    float so = 0, sp = 0, sb = 0, sc = 0, sn = 0;
    for (int i = tid; i < nobj; i += 256) so += pobj[i];
    for (int i = tid; i < nfg; i += 256) {
        const float4 v = ((const float4*)pfg)[i];
        sp += v.x; sb += v.y; sc += v.z; sn += v.w;
    }
    __shared__ float red[256];
    float in5[5] = {so, sp, sb, sc, sn};
    float res[5];
    #pragma unroll
    for (int k = 0; k < 5; ++k) {
        red[tid] = in5[k];
        __syncthreads();
        for (int s = 128; s > 0; s >>= 1) {
            if (tid < s) red[tid] += red[tid + s];
            __syncthreads();
        }
        res[k] = red[0];
        __syncthreads();
    }
    if (tid == 0) {
        const float obj_sum = res[0] - res[1]; // sum softplus(po) - sum_{fg} po
        const float n_pos = fmaxf(res[4], 1.0f);
        const float total = 7.5f * res[2] / n_pos
                          + 0.5f * res[3] / n_pos
                          + obj_sum / (float)N_;
        out[0] = total;
    }
}

extern "C" void kernel_launch(void* const* d_in, const int* in_sizes, int n_in,
                              void* d_out, int out_size, void* d_ws, size_t ws_size,
                              hipStream_t stream)
{
    const float* pred = (const float*)d_in[0];
    const float* gtb  = (const float*)d_in[1];
    const int*   gtc  = (const int*)d_in[2];
    const float* anc  = (const float*)d_in[3];

    char* ws = (char*)d_ws;
    size_t off = 0;
    auto take = [&](size_t bytes) {
        size_t o = off;
        off += (bytes + 255) & ~(size_t)255;
        return o;
    };
    unsigned char*      mask   = (unsigned char*)(ws + take((size_t)B_ * N_));
    int*                cidx   = (int*)(ws + take((size_t)B_ * N_ * 4));
    float*              spsum  = (float*)(ws + take((size_t)B_ * N_ * 4));
    int*                counts = (int*)(ws + take((size_t)B_ * 2 * 4));
    unsigned long long* bkey   = (unsigned long long*)(ws + take((size_t)B_ * N_ * 8));
    const int nblk = (N_ + 255) / 256; // 132
    float*              pobj   = (float*)(ws + take((size_t)OBJ_BLOCKS * 4));
    float*              pfg    = (float*)(ws + take((size_t)nblk * B_ * 4 * 4));

    hipMemsetAsync(bkey, 0xFF, (size_t)B_ * N_ * 8, stream);

    dim3 gA(nblk, B_);
    k_cand<<<gA, 256, 0, stream>>>(gtb, anc, pred, mask, spsum);
    k_compact<<<B_, 256, 0, stream>>>(mask, cidx, counts);
    dim3 gT(G_, B_);
    k_topk<<<gT, 64, 0, stream>>>(pred, gtb, gtc, cidx, counts, spsum, bkey);
    k_obj<<<OBJ_BLOCKS, 256, 0, stream>>>(pred, pobj);
    k_fg<<<gA, 256, 0, stream>>>(pred, gtb, gtc, bkey, pfg);
    k_final<<<1, 256, 0, stream>>>(pobj, OBJ_BLOCKS, pfg, nblk * B_, (float*)d_out);
}

// Round 3
// 117.075 us; speedup vs baseline: 2.3970x; 2.3970x over previous
//
#include <hip/hip_runtime.h>
#include <math.h>

#define B_ 4
#define N_ 33600
#define G_ 100
#define NCLS 80
#define STRIDE 85   // 4 box + 80 cls + 1 obj
#define TK 10
#define OF_BLOCKS 1024

__device__ __forceinline__ float sigmoidf_(float x) {
    return 1.0f / (1.0f + expf(-x));
}
__device__ __forceinline__ float softplusf_(float x) {
    return fmaxf(x, 0.0f) + log1pf(expf(-fabsf(x)));
}
__device__ __forceinline__ float waveRedSum(float v) {
    #pragma unroll
    for (int off = 32; off; off >>= 1) v += __shfl_xor(v, off, 64);
    return v;
}

// ---------------------------------------------------------------- stage 1
// candidate mask only: anchor within CENTER_RADIUS of any GT center.
// Branchless OR over all 100 GTs -> unrollable, batched LDS reads.
__global__ void k_cand(const float* __restrict__ gtb,
                       const float* __restrict__ anc,
                       unsigned char* __restrict__ mask)
{
    __shared__ float gcx[G_], gcy[G_];
    const int b = blockIdx.y;
    const int tid = threadIdx.x;
    if (tid < G_) {
        gcx[tid] = gtb[(b * G_ + tid) * 4 + 0];
        gcy[tid] = gtb[(b * G_ + tid) * 4 + 1];
    }
    __syncthreads();
    const int n = blockIdx.x * blockDim.x + tid;
    if (n >= N_) return;
    const float2 a = ((const float2*)anc)[n];
    int c = 0;
    #pragma unroll 10
    for (int g = 0; g < G_; ++g) {
        const float dx = a.x - gcx[g], dy = a.y - gcy[g];
        c |= (dx * dx + dy * dy < 6.25f) ? 1 : 0;
    }
    mask[b * N_ + n] = (unsigned char)c;
}

// ---------------------------------------------------------------- stage 2
// ordered compaction, one block per image, 16 mask bytes per thread per chunk
__global__ void k_compact(const unsigned char* __restrict__ mask,
                          int* __restrict__ cidx,
                          int* __restrict__ counts) // [b][0]=n_cand, [b][1]=all_cand
{
    const int b = blockIdx.x;
    const int tid = threadIdx.x;
    const int lane = tid & 63, wid = tid >> 6;
    __shared__ int wsum[4];
    int base = 0;
    const int CH = 4096; // 256 threads * 16 bytes
    for (int chunk = 0; chunk * CH < N_; ++chunk) {
        const int i0 = chunk * CH + tid * 16;
        uint4 v = make_uint4(0, 0, 0, 0);
        // 33600 = 8*4096 + 832; 832 = 52*16 -> in-range is 16B-granular
        if (i0 + 16 <= N_) v = *reinterpret_cast<const uint4*>(mask + (size_t)b * N_ + i0);
        // mask bytes are 0/1, so popcount == byte sum
        const int cnt = __popc(v.x) + __popc(v.y) + __popc(v.z) + __popc(v.w);
        int incl = cnt;
        #pragma unroll
        for (int off = 1; off < 64; off <<= 1) {
            const int t = __shfl_up(incl, off, 64);
            if (lane >= off) incl += t;
        }
        if (lane == 63) wsum[wid] = incl;
        __syncthreads();
        int wbase = 0;
        for (int w = 0; w < wid; ++w) wbase += wsum[w];
        const int ctot = wsum[0] + wsum[1] + wsum[2] + wsum[3];
        int pos = base + wbase + (incl - cnt);
        if (cnt) {
            const unsigned w4[4] = {v.x, v.y, v.z, v.w};
            #pragma unroll
            for (int j = 0; j < 16; ++j) {
                if ((w4[j >> 2] >> ((j & 3) * 8)) & 1u)
                    cidx[(size_t)b * N_ + pos++] = i0 + j;
            }
        }
        base += ctot;
        __syncthreads();
    }
    if (tid == 0) {
        counts[b * 2 + 0] = base;
        counts[b * 2 + 1] = (base == 0) ? 1 : 0; // fallback: all anchors candidates
    }
}

// ---------------------------------------------------------------- stage 3
// one WAVE per candidate; lanes parallel over the 80 classes.
// spsum is indexed by compacted slot i (coalesced read in k_topk).
__global__ void k_spsum(const float* __restrict__ pred,
                        const int* __restrict__ cidx,
                        const int* __restrict__ counts,
                        float* __restrict__ spsum)
{
    const int b = blockIdx.y;
    const int cnt = counts[b * 2 + 0];
    const int allc = counts[b * 2 + 1];
    if (allc) return; // never-taken fallback: k_topk computes on the fly
    const int tid = threadIdx.x;
    const int lane = tid & 63, wid = tid >> 6;
    const int wavesPerImg = gridDim.x * (blockDim.x >> 6);
    const int w0 = blockIdx.x * (blockDim.x >> 6) + wid;
    for (int i = w0; i < cnt; i += wavesPerImg) {
        const int n = cidx[(size_t)b * N_ + i];
        const float* row = pred + (size_t)(b * N_ + n) * STRIDE + 4;
        float s = softplusf_(sigmoidf_(row[lane]));
        if (lane < NCLS - 64) s += softplusf_(sigmoidf_(row[64 + lane]));
        s = waveRedSum(s);
        if (lane == 0) spsum[(size_t)b * N_ + i] = s;
    }
}

// ---------------------------------------------------------------- stage 4
// one wave per (b,g): iou col-sum -> dyn_k; stable top-10 smallest cost;
// scatter atomicMin((cost_bits<<32)|g) per kept anchor.
__global__ void __launch_bounds__(64)
k_topk(const float* __restrict__ pred,
       const float* __restrict__ gtb,
       const int* __restrict__ gtc,
       const int* __restrict__ cidx,
       const int* __restrict__ counts,
       const float* __restrict__ spsum,
       unsigned long long* __restrict__ bkey)
{
    const int b = blockIdx.y, g = blockIdx.x;
    const int lane = threadIdx.x;
    const int cnt = counts[b * 2 + 0];
    const int allc = counts[b * 2 + 1];
    const int count = allc ? N_ : cnt;

    const float* gb = gtb + (b * G_ + g) * 4;
    const float gxc = gb[0], gyc = gb[1], gw = gb[2], gh = gb[3];
    const float gx1 = gxc - gw * 0.5f, gy1 = gyc - gh * 0.5f;
    const float gx2 = gxc + gw * 0.5f, gy2 = gyc + gh * 0.5f;
    const float garea = gw * gh;
    const int cls = gtc[b * G_ + g];

    float kcost[TK];
    int   kslot[TK];
    #pragma unroll
    for (int j = 0; j < TK; ++j) { kcost[j] = INFINITY; kslot[j] = 0x7FFFFFFF; }

    float iousum = 0.0f;
    for (int i = lane; i < count; i += 64) {
        const int n = allc ? i : cidx[(size_t)b * N_ + i];
        const float* pr = pred + (size_t)(b * N_ + n) * STRIDE;
        const float px = pr[0], py = pr[1], pw = pr[2], ph = pr[3];
        const float x1 = px - pw * 0.5f, y1 = py - ph * 0.5f;
        const float x2 = px + pw * 0.5f, y2 = py + ph * 0.5f;
        const float iw = fmaxf(fminf(x2, gx2) - fmaxf(x1, gx1), 0.0f);
        const float ih = fmaxf(fminf(y2, gy2) - fmaxf(y1, gy1), 0.0f);
        const float inter = iw * ih;
        const float uni = pw * ph + garea - inter + 1e-7f;
        const float iou = inter / uni;
        iousum += iou;
        const float sgc = sigmoidf_(pr[4 + cls]);
        float sp;
        if (allc) { // never taken in practice (no-candidate fallback)
            float s = 0.0f;
            for (int cc = 0; cc < NCLS; ++cc) s += softplusf_(sigmoidf_(pr[4 + cc]));
            sp = s;
        } else {
            sp = spsum[(size_t)b * N_ + i];
        }
        float c = -logf(iou + 1e-8f) + 3.0f * (sp - sgc);
        int   s = i;
        // bubble-insert; slots within a lane strictly increase, so strict <
        // preserves lexicographic (cost, slot) order.
        #pragma unroll
        for (int j = 0; j < TK; ++j) {
            const bool lt = (c < kcost[j]);
            const float tc = kcost[j]; const int ts = kslot[j];
            if (lt) { kcost[j] = c; kslot[j] = s; c = tc; s = ts; }
        }
    }

    // wave-sum of iou column
    #pragma unroll
    for (int off = 32; off; off >>= 1) iousum += __shfl_xor(iousum, off, 64);

    // 10 rounds of wave-wide extract-min on packed (cost_bits, slot) keys.
    // cost > 0 always (cls_cost >= ~54), so float bits are order-preserving.
    unsigned long long win[TK];
    #pragma unroll
    for (int r = 0; r < TK; ++r) {
        const unsigned long long mykey =
            ((unsigned long long)__float_as_uint(kcost[0]) << 32) | (unsigned)kslot[0];
        unsigned long long k2 = mykey;
        #pragma unroll
        for (int off = 32; off; off >>= 1) {
            const unsigned long long o = __shfl_xor(k2, off, 64);
            k2 = (o < k2) ? o : k2;
        }
        win[r] = k2;
        if (mykey == k2) { // unique (slot unique per lane); pop my head
            #pragma unroll
            for (int j = 0; j < TK - 1; ++j) { kcost[j] = kcost[j + 1]; kslot[j] = kslot[j + 1]; }
            kcost[TK - 1] = INFINITY; kslot[TK - 1] = 0x7FFFFFFF;
        }
    }

    const int kmax = (count < TK) ? count : TK;
    int dk = (int)floorf(iousum);
    if (dk < 1) dk = 1;
    if (dk > kmax) dk = kmax;

    if (lane == 0) {
        #pragma unroll
        for (int r = 0; r < TK; ++r) {
            if (r < dk) {
                const unsigned slot = (unsigned)(win[r] & 0xFFFFFFFFull);
                const int n = allc ? (int)slot : cidx[(size_t)b * N_ + (int)slot];
                const unsigned cbits = (unsigned)(win[r] >> 32);
                const unsigned long long key =
                    ((unsigned long long)cbits << 32) | (unsigned)g;
                atomicMin(&bkey[(size_t)b * N_ + n], key);
            }
        }
    }
}

// ---------------------------------------------------------------- stage 5
// merged: (phase 1) coalesced stream of ALL of pred summing softplus(obj);
// (phase 2) fg-only CIoU + focal cls + npos + fg obj-logit sum.
// partials: 8 floats per block = {so, posum, box, cls} {npos, 0,0,0}
__global__ void k_objfg(const float* __restrict__ pred,
                        const float* __restrict__ gtb,
                        const int* __restrict__ gtc,
                        const unsigned long long* __restrict__ bkey,
                        float* __restrict__ part)
{
    const int tid = threadIdx.x;
    float so = 0.0f, posum = 0.0f, box = 0.0f, cls = 0.0f, npos = 0.0f;

    // phase 1: obj logit lives at flat column 84 of each 85-wide row;
    // a float4 at flat index i contains it iff (4i)%85 >= 81.
    {
        const float4* p4 = (const float4*)pred;
        const unsigned T = (unsigned)(B_ * N_ * STRIDE / 4); // 2,856,000
        for (unsigned i = blockIdx.x * blockDim.x + tid; i < T;
             i += gridDim.x * blockDim.x) {
            const float4 v = p4[i];
            const unsigned c0 = (i * 4u) % 85u;
            if (c0 >= 81u) {
                const float x = (c0 == 84u) ? v.x
                              : (c0 == 83u) ? v.y
                              : (c0 == 82u) ? v.z : v.w;
                so += softplusf_(x);
            }
        }
    }

    // phase 2: per-anchor fg terms
    for (unsigned i = blockIdx.x * blockDim.x + tid; i < (unsigned)(B_ * N_);
         i += gridDim.x * blockDim.x) {
        const unsigned long long key = bkey[i];
        if (key != 0xFFFFFFFFFFFFFFFFull) {
            const int b = (int)(i / N_);
            const int mg = (int)(unsigned)(key & 0xFFFFFFFFull);
            const float* pr = pred + (size_t)i * STRIDE;
            const float* gb = gtb + (b * G_ + mg) * 4;
            npos += 1.0f;
            posum += pr[STRIDE - 1];
            const float px = pr[0], py = pr[1], pw = pr[2], ph = pr[3];
            const float gx = gb[0], gy = gb[1], gw = gb[2], gh = gb[3];
            const float x11 = px - pw * 0.5f, y11 = py - ph * 0.5f;
            const float x12 = px + pw * 0.5f, y12 = py + ph * 0.5f;
            const float x21 = gx - gw * 0.5f, y21 = gy - gh * 0.5f;
            const float x22 = gx + gw * 0.5f, y22 = gy + gh * 0.5f;
            const float iw = fmaxf(fminf(x12, x22) - fmaxf(x11, x21), 0.0f);
            const float ih = fmaxf(fminf(y12, y22) - fmaxf(y11, y21), 0.0f);
            const float inter = iw * ih;
            const float uni = pw * ph + gw * gh - inter + 1e-7f;
            const float iou = inter / uni;
            const float cw = fmaxf(x12, x22) - fminf(x11, x21);
            const float chh = fmaxf(y12, y22) - fminf(y11, y21);
            const float c2 = cw * cw + chh * chh + 1e-7f;
            const float ddx = x11 + x12 - x21 - x22;
            const float ddy = y11 + y12 - y21 - y22;
            const float rho2 = (ddx * ddx + ddy * ddy) * 0.25f;
            const float dv = atanf(gw / (gh + 1e-7f)) - atanf(pw / (ph + 1e-7f));
            const float v = (float)(4.0 / (M_PI * M_PI)) * dv * dv;
            const float alpha = v / (v - iou + 1.0f + 1e-7f);
            const float ciou = iou - (rho2 / c2 + v * alpha);
            box += 1.0f - ciou;
            const int cg = gtc[b * G_ + mg];
            float csum = 0.0f;
            for (int c = 0; c < NCLS; ++c) {
                const float x = pr[4 + c];
                const float t = (c == cg) ? 1.0f : 0.0f;
                const float bce = softplusf_(x) - x * t;
                const float p = sigmoidf_(x);
                const float pt = (c == cg) ? p : (1.0f - p);
                const float om = 1.0f - pt;
                csum += 0.25f * om * om * bce;
            }
            cls += csum;
        }
    }

    so = waveRedSum(so);
    posum = waveRedSum(posum);
    box = waveRedSum(box);
    cls = waveRedSum(cls);
    npos = waveRedSum(npos);
    __shared__ float ws[4][5];
    const int lane = tid & 63, wid = tid >> 6;
    if (lane == 0) {
        ws[wid][0] = so; ws[wid][1] = posum; ws[wid][2] = box;
        ws[wid][3] = cls; ws[wid][4] = npos;
    }
    __syncthreads();
    if (tid == 0) {
        float r[5];
        #pragma unroll
        for (int k = 0; k < 5; ++k)
            r[k] = ws[0][k] + ws[1][k] + ws[2][k] + ws[3][k];
        float4* p = (float4*)part;
        p[blockIdx.x * 2 + 0] = make_float4(r[0], r[1], r[2], r[3]);
        p[blockIdx.x * 2 + 1] = make_float4(r[4], 0.0f, 0.0f, 0.0f);
    }
}

// ---------------------------------------------------------------- stage 6
__global__ void k_final(const float* __restrict__ part, int nblocks,
                        float* __restrict__ out)
{
    const int tid = threadIdx.x;
    float so = 0, sp = 0, sb = 0, sc = 0, sn = 0;
    for (int i = tid; i < nblocks; i += 256) {
        const float4 a = ((const float4*)part)[i * 2 + 0];
        const float4 b = ((const float4*)part)[i * 2 + 1];
        so += a.x; sp += a.y; sb += a.z; sc += a.w; sn += b.x;
    }
    __shared__ float red[256];
    float in5[5] = {so, sp, sb, sc, sn};
    float res[5];
    #pragma unroll
    for (int k = 0; k < 5; ++k) {
        red[tid] = in5[k];
        __syncthreads();
        for (int s = 128; s > 0; s >>= 1) {
            if (tid < s) red[tid] += red[tid + s];
            __syncthreads();
        }
        res[k] = red[0];
        __syncthreads();
    }
    if (tid == 0) {
        const float obj_sum = res[0] - res[1]; // sum softplus(po) - sum_{fg} po
        const float n_pos = fmaxf(res[4], 1.0f);
        const float total = 7.5f * res[2] / n_pos
                          + 0.5f * res[3] / n_pos
                          + obj_sum / (float)N_;
        out[0] = total;
    }
}

extern "C" void kernel_launch(void* const* d_in, const int* in_sizes, int n_in,
                              void* d_out, int out_size, void* d_ws, size_t ws_size,
                              hipStream_t stream)
{
    const float* pred = (const float*)d_in[0];
    const float* gtb  = (const float*)d_in[1];
    const int*   gtc  = (const int*)d_in[2];
    const float* anc  = (const float*)d_in[3];

    char* ws = (char*)d_ws;
    size_t off = 0;
    auto take = [&](size_t bytes) {
        size_t o = off;
        off += (bytes + 255) & ~(size_t)255;
        return o;
    };
    unsigned char*      mask   = (unsigned char*)(ws + take((size_t)B_ * N_));
    int*                cidx   = (int*)(ws + take((size_t)B_ * N_ * 4));
    float*              spsum  = (float*)(ws + take((size_t)B_ * N_ * 4));
    int*                counts = (int*)(ws + take((size_t)B_ * 2 * 4));
    unsigned long long* bkey   = (unsigned long long*)(ws + take((size_t)B_ * N_ * 8));
    float*              part   = (float*)(ws + take((size_t)OF_BLOCKS * 8 * 4));

    hipMemsetAsync(bkey, 0xFF, (size_t)B_ * N_ * 8, stream);

    const int nblk = (N_ + 255) / 256; // 132
    dim3 gA(nblk, B_);
    k_cand<<<gA, 256, 0, stream>>>(gtb, anc, mask);
    k_compact<<<B_, 256, 0, stream>>>(mask, cidx, counts);
    dim3 gS(32, B_);
    k_spsum<<<gS, 256, 0, stream>>>(pred, cidx, counts, spsum);
    dim3 gT(G_, B_);
    k_topk<<<gT, 64, 0, stream>>>(pred, gtb, gtc, cidx, counts, spsum, bkey);
    k_objfg<<<OF_BLOCKS, 256, 0, stream>>>(pred, gtb, gtc, bkey, part);
    k_final<<<1, 256, 0, stream>>>(part, OF_BLOCKS, (float*)d_out);
}

// Round 4
// 49.949 us; speedup vs baseline: 5.6183x; 2.3439x over previous
//
#include <hip/hip_runtime.h>
#include <math.h>

#define B_ 4
#define N_ 33600
#define G_ 100
#define NCLS 80
#define STRIDE 85   // 4 box + 80 cls + 1 obj
#define TK 10
#define NBLK 525    // B_*N_ / 256 exactly

__device__ __forceinline__ float sigmoidf_(float x) {
    return 1.0f / (1.0f + expf(-x));
}
__device__ __forceinline__ float softplusf_(float x) {
    return fmaxf(x, 0.0f) + log1pf(expf(-fabsf(x)));
}
__device__ __forceinline__ float waveRedSum(float v) {
    #pragma unroll
    for (int off = 32; off; off >>= 1) v += __shfl_xor(v, off, 64);
    return v;
}

// ---------------------------------------------------------------- stage 1
// candidate mask: anchor within CENTER_RADIUS of any GT center (branchless)
__global__ void k_cand(const float* __restrict__ gtb,
                       const float* __restrict__ anc,
                       unsigned char* __restrict__ mask)
{
    __shared__ float gcx[G_], gcy[G_];
    const int b = blockIdx.y;
    const int tid = threadIdx.x;
    if (tid < G_) {
        gcx[tid] = gtb[(b * G_ + tid) * 4 + 0];
        gcy[tid] = gtb[(b * G_ + tid) * 4 + 1];
    }
    __syncthreads();
    const int n = blockIdx.x * blockDim.x + tid;
    if (n >= N_) return;
    const float2 a = ((const float2*)anc)[n];
    int c = 0;
    #pragma unroll 10
    for (int g = 0; g < G_; ++g) {
        const float dx = a.x - gcx[g], dy = a.y - gcy[g];
        c |= (dx * dx + dy * dy < 6.25f) ? 1 : 0;
    }
    mask[b * N_ + n] = (unsigned char)c;
}

// ---------------------------------------------------------------- stage 2
// ordered compaction, one block per image, 16 mask bytes per thread per chunk
__global__ void k_compact(const unsigned char* __restrict__ mask,
                          int* __restrict__ cidx,
                          int* __restrict__ counts) // [b][0]=n_cand, [b][1]=all_cand
{
    const int b = blockIdx.x;
    const int tid = threadIdx.x;
    const int lane = tid & 63, wid = tid >> 6;
    __shared__ int wsum[4];
    int base = 0;
    const int CH = 4096; // 256 threads * 16 bytes
    for (int chunk = 0; chunk * CH < N_; ++chunk) {
        const int i0 = chunk * CH + tid * 16;
        uint4 v = make_uint4(0, 0, 0, 0);
        if (i0 + 16 <= N_) v = *reinterpret_cast<const uint4*>(mask + (size_t)b * N_ + i0);
        const int cnt = __popc(v.x) + __popc(v.y) + __popc(v.z) + __popc(v.w);
        int incl = cnt;
        #pragma unroll
        for (int off = 1; off < 64; off <<= 1) {
            const int t = __shfl_up(incl, off, 64);
            if (lane >= off) incl += t;
        }
        if (lane == 63) wsum[wid] = incl;
        __syncthreads();
        int wbase = 0;
        for (int w = 0; w < wid; ++w) wbase += wsum[w];
        const int ctot = wsum[0] + wsum[1] + wsum[2] + wsum[3];
        int pos = base + wbase + (incl - cnt);
        if (cnt) {
            const unsigned w4[4] = {v.x, v.y, v.z, v.w};
            #pragma unroll
            for (int j = 0; j < 16; ++j) {
                if ((w4[j >> 2] >> ((j & 3) * 8)) & 1u)
                    cidx[(size_t)b * N_ + pos++] = i0 + j;
            }
        }
        base += ctot;
        __syncthreads();
    }
    if (tid == 0) {
        counts[b * 2 + 0] = base;
        counts[b * 2 + 1] = (base == 0) ? 1 : 0; // fallback: all anchors candidates
    }
}

// ---------------------------------------------------------------- stage 3
// one WAVE per candidate: lanes over classes for spsum; cache per-slot
// features {x1,y1,x2,y2,area,spsum} for k_topk's coalesced consumption.
__global__ void k_cfeat(const float* __restrict__ pred,
                        const int* __restrict__ cidx,
                        const int* __restrict__ counts,
                        float* __restrict__ cfeat) // [B][N][8] slot-indexed
{
    const int b = blockIdx.y;
    const int cnt = counts[b * 2 + 0];
    const int allc = counts[b * 2 + 1];
    if (allc) return; // never-taken fallback handled in k_topk
    const int tid = threadIdx.x;
    const int lane = tid & 63, wid = tid >> 6;
    const int wavesPerImg = gridDim.x * (blockDim.x >> 6);
    const int w0 = blockIdx.x * (blockDim.x >> 6) + wid;
    for (int i = w0; i < cnt; i += wavesPerImg) {
        const int n = cidx[(size_t)b * N_ + i];
        const float* row = pred + (size_t)(b * N_ + n) * STRIDE;
        float s = softplusf_(sigmoidf_(row[4 + lane]));
        if (lane < NCLS - 64) s += softplusf_(sigmoidf_(row[4 + 64 + lane]));
        s = waveRedSum(s);
        if (lane == 0) {
            const float px = row[0], py = row[1], pw = row[2], ph = row[3];
            float* cf = cfeat + (size_t)(b * N_ + i) * 8;
            cf[0] = px - pw * 0.5f;
            cf[1] = py - ph * 0.5f;
            cf[2] = px + pw * 0.5f;
            cf[3] = py + ph * 0.5f;
            cf[4] = pw * ph;
            cf[5] = s;
        }
    }
}

// ---------------------------------------------------------------- stage 4
// one wave per (b,g): iou col-sum -> dyn_k; stable top-10 smallest cost;
// scatter atomicMin((cost_bits<<32)|g) per kept anchor.
__global__ void __launch_bounds__(64)
k_topk(const float* __restrict__ pred,
       const float* __restrict__ gtb,
       const int* __restrict__ gtc,
       const int* __restrict__ cidx,
       const int* __restrict__ counts,
       const float* __restrict__ cfeat,
       unsigned long long* __restrict__ bkey)
{
    const int b = blockIdx.y, g = blockIdx.x;
    const int lane = threadIdx.x;
    const int cnt = counts[b * 2 + 0];
    const int allc = counts[b * 2 + 1];
    const int count = allc ? N_ : cnt;

    const float* gb = gtb + (b * G_ + g) * 4;
    const float gxc = gb[0], gyc = gb[1], gw = gb[2], gh = gb[3];
    const float gx1 = gxc - gw * 0.5f, gy1 = gyc - gh * 0.5f;
    const float gx2 = gxc + gw * 0.5f, gy2 = gyc + gh * 0.5f;
    const float garea = gw * gh;
    const int cls = gtc[b * G_ + g];

    float kcost[TK];
    int   kslot[TK];
    #pragma unroll
    for (int j = 0; j < TK; ++j) { kcost[j] = INFINITY; kslot[j] = 0x7FFFFFFF; }

    float iousum = 0.0f;
    for (int i = lane; i < count; i += 64) {
        float x1, y1, x2, y2, parea, sp;
        int n;
        if (allc) { // never taken in practice (no-candidate fallback)
            n = i;
            const float* pr = pred + (size_t)(b * N_ + n) * STRIDE;
            const float px = pr[0], py = pr[1], pw = pr[2], ph = pr[3];
            x1 = px - pw * 0.5f; y1 = py - ph * 0.5f;
            x2 = px + pw * 0.5f; y2 = py + ph * 0.5f;
            parea = pw * ph;
            float s = 0.0f;
            for (int cc = 0; cc < NCLS; ++cc) s += softplusf_(sigmoidf_(pr[4 + cc]));
            sp = s;
        } else {
            n = cidx[(size_t)b * N_ + i];
            const float* cf = cfeat + (size_t)(b * N_ + i) * 8;
            x1 = cf[0]; y1 = cf[1]; x2 = cf[2]; y2 = cf[3];
            parea = cf[4]; sp = cf[5];
        }
        const float iw = fmaxf(fminf(x2, gx2) - fmaxf(x1, gx1), 0.0f);
        const float ih = fmaxf(fminf(y2, gy2) - fmaxf(y1, gy1), 0.0f);
        const float inter = iw * ih;
        const float uni = parea + garea - inter + 1e-7f;
        const float iou = inter / uni;
        iousum += iou;
        const float sgc = sigmoidf_(pred[(size_t)(b * N_ + n) * STRIDE + 4 + cls]);
        float c = -logf(iou + 1e-8f) + 3.0f * (sp - sgc);
        int   s = i;
        // bubble-insert; slots within a lane strictly increase, so strict <
        // preserves lexicographic (cost, slot) order.
        #pragma unroll
        for (int j = 0; j < TK; ++j) {
            const bool lt = (c < kcost[j]);
            const float tc = kcost[j]; const int ts = kslot[j];
            if (lt) { kcost[j] = c; kslot[j] = s; c = tc; s = ts; }
        }
    }

    // wave-sum of iou column
    #pragma unroll
    for (int off = 32; off; off >>= 1) iousum += __shfl_xor(iousum, off, 64);

    // 10 rounds of wave-wide extract-min on packed (cost_bits, slot) keys.
    // cost > 0 always (cls_cost >= ~54), so float bits are order-preserving.
    unsigned long long win[TK];
    #pragma unroll
    for (int r = 0; r < TK; ++r) {
        const unsigned long long mykey =
            ((unsigned long long)__float_as_uint(kcost[0]) << 32) | (unsigned)kslot[0];
        unsigned long long k2 = mykey;
        #pragma unroll
        for (int off = 32; off; off >>= 1) {
            const unsigned long long o = __shfl_xor(k2, off, 64);
            k2 = (o < k2) ? o : k2;
        }
        win[r] = k2;
        if (mykey == k2) { // unique (slot unique per lane); pop my head
            #pragma unroll
            for (int j = 0; j < TK - 1; ++j) { kcost[j] = kcost[j + 1]; kslot[j] = kslot[j + 1]; }
            kcost[TK - 1] = INFINITY; kslot[TK - 1] = 0x7FFFFFFF;
        }
    }

    const int kmax = (count < TK) ? count : TK;
    int dk = (int)floorf(iousum);
    if (dk < 1) dk = 1;
    if (dk > kmax) dk = kmax;

    if (lane == 0) {
        #pragma unroll
        for (int r = 0; r < TK; ++r) {
            if (r < dk) {
                const unsigned slot = (unsigned)(win[r] & 0xFFFFFFFFull);
                const int n = allc ? (int)slot : cidx[(size_t)b * N_ + (int)slot];
                const unsigned cbits = (unsigned)(win[r] >> 32);
                const unsigned long long key =
                    ((unsigned long long)cbits << 32) | (unsigned)g;
                atomicMin(&bkey[(size_t)b * N_ + n], key);
            }
        }
    }
}

// ---------------------------------------------------------------- stage 5
// obj-sum: one thread per anchor row, single gathered load of the obj logit
__global__ void k_obj(const float* __restrict__ pred,
                      float* __restrict__ pobj)
{
    const int tid = threadIdx.x;
    const unsigned i = blockIdx.x * blockDim.x + tid; // < B_*N_ exactly
    float so = softplusf_(pred[(size_t)i * STRIDE + (STRIDE - 1)]);
    so = waveRedSum(so);
    __shared__ float ws[4];
    const int lane = tid & 63, wid = tid >> 6;
    if (lane == 0) ws[wid] = so;
    __syncthreads();
    if (tid == 0) pobj[blockIdx.x] = ws[0] + ws[1] + ws[2] + ws[3];
}

// ---------------------------------------------------------------- stage 6
// fg terms, wave-cooperative: ballot fg lanes, whole wave does focal over
// classes (lane -> class, coalesced row read); lane 0 does CIoU.
__global__ void k_fg(const float* __restrict__ pred,
                     const float* __restrict__ gtb,
                     const int* __restrict__ gtc,
                     const unsigned long long* __restrict__ bkey,
                     float* __restrict__ pfg)
{
    const int tid = threadIdx.x;
    const unsigned i = blockIdx.x * blockDim.x + tid; // anchor flat id, < B_*N_
    const int lane = tid & 63, wid = tid >> 6;
    const unsigned long long key = bkey[i];
    const bool fg = (key != 0xFFFFFFFFFFFFFFFFull);
    float posum = 0.0f, box = 0.0f, clsacc = 0.0f, npos = 0.0f;

    unsigned long long m = __ballot(fg);
    while (m) {
        const int src = (int)__ffsll((unsigned long long)m) - 1;
        m &= (m - 1);
        const unsigned ai = (unsigned)__shfl((int)i, src, 64);
        const int mg = __shfl((int)(unsigned)(key & 0xFFFFFFFFull), src, 64);
        const int b = (int)(ai / (unsigned)N_);
        const float* pr = pred + (size_t)ai * STRIDE;
        const int cg = gtc[b * G_ + mg];
        // focal term: lane handles class `lane` (and `64+lane` for lane<16)
        {
            const float x = pr[4 + lane];
            const float t = (lane == cg) ? 1.0f : 0.0f;
            const float bce = softplusf_(x) - x * t;
            const float p = sigmoidf_(x);
            const float pt = t * p + (1.0f - t) * (1.0f - p);
            const float om = 1.0f - pt;
            clsacc += 0.25f * om * om * bce;
        }
        if (lane < NCLS - 64) {
            const float x = pr[4 + 64 + lane];
            const float t = ((64 + lane) == cg) ? 1.0f : 0.0f;
            const float bce = softplusf_(x) - x * t;
            const float p = sigmoidf_(x);
            const float pt = t * p + (1.0f - t) * (1.0f - p);
            const float om = 1.0f - pt;
            clsacc += 0.25f * om * om * bce;
        }
        if (lane == 0) {
            npos += 1.0f;
            posum += pr[STRIDE - 1];
            const float* gb = gtb + (b * G_ + mg) * 4;
            const float px = pr[0], py = pr[1], pw = pr[2], ph = pr[3];
            const float gx = gb[0], gy = gb[1], gw = gb[2], gh = gb[3];
            const float x11 = px - pw * 0.5f, y11 = py - ph * 0.5f;
            const float x12 = px + pw * 0.5f, y12 = py + ph * 0.5f;
            const float x21 = gx - gw * 0.5f, y21 = gy - gh * 0.5f;
            const float x22 = gx + gw * 0.5f, y22 = gy + gh * 0.5f;
            const float iw = fmaxf(fminf(x12, x22) - fmaxf(x11, x21), 0.0f);
            const float ih = fmaxf(fminf(y12, y22) - fmaxf(y11, y21), 0.0f);
            const float inter = iw * ih;
            const float uni = pw * ph + gw * gh - inter + 1e-7f;
            const float iou = inter / uni;
            const float cw = fmaxf(x12, x22) - fminf(x11, x21);
            const float chh = fmaxf(y12, y22) - fminf(y11, y21);
            const float c2 = cw * cw + chh * chh + 1e-7f;
            const float ddx = x11 + x12 - x21 - x22;
            const float ddy = y11 + y12 - y21 - y22;
            const float rho2 = (ddx * ddx + ddy * ddy) * 0.25f;
            const float dv = atanf(gw / (gh + 1e-7f)) - atanf(pw / (ph + 1e-7f));
            const float v = (float)(4.0 / (M_PI * M_PI)) * dv * dv;
            const float alpha = v / (v - iou + 1.0f + 1e-7f);
            const float ciou = iou - (rho2 / c2 + v * alpha);
            box += 1.0f - ciou;
        }
    }

    posum = waveRedSum(posum);
    box = waveRedSum(box);
    clsacc = waveRedSum(clsacc);
    npos = waveRedSum(npos);
    __shared__ float ws[4][4];
    if (lane == 0) {
        ws[wid][0] = posum; ws[wid][1] = box;
        ws[wid][2] = clsacc; ws[wid][3] = npos;
    }
    __syncthreads();
    if (tid == 0) {
        ((float4*)pfg)[blockIdx.x] = make_float4(
            ws[0][0] + ws[1][0] + ws[2][0] + ws[3][0],
            ws[0][1] + ws[1][1] + ws[2][1] + ws[3][1],
            ws[0][2] + ws[1][2] + ws[2][2] + ws[3][2],
            ws[0][3] + ws[1][3] + ws[2][3] + ws[3][3]);
    }
}

// ---------------------------------------------------------------- stage 7
__global__ void k_final(const float* __restrict__ pobj,
                        const float* __restrict__ pfg, int nblocks,
                        float* __restrict__ out)
{
    const int tid = threadIdx.x;
    float so = 0, sp = 0, sb = 0, sc = 0, sn = 0;
    for (int i = tid; i < nblocks; i += 256) {
        so += pobj[i];
        const float4 v = ((const float4*)pfg)[i];
        sp += v.x; sb += v.y; sc += v.z; sn += v.w;
    }
    __shared__ float red[256];
    float in5[5] = {so, sp, sb, sc, sn};
    float res[5];
    #pragma unroll
    for (int k = 0; k < 5; ++k) {
        red[tid] = in5[k];
        __syncthreads();
        for (int s = 128; s > 0; s >>= 1) {
            if (tid < s) red[tid] += red[tid + s];
            __syncthreads();
        }
        res[k] = red[0];
        __syncthreads();
    }
    if (tid == 0) {
        const float obj_sum = res[0] - res[1]; // sum softplus(po) - sum_{fg} po
        const float n_pos = fmaxf(res[4], 1.0f);
        const float total = 7.5f * res[2] / n_pos
                          + 0.5f * res[3] / n_pos
                          + obj_sum / (float)N_;
        out[0] = total;
    }
}

extern "C" void kernel_launch(void* const* d_in, const int* in_sizes, int n_in,
                              void* d_out, int out_size, void* d_ws, size_t ws_size,
                              hipStream_t stream)
{
    const float* pred = (const float*)d_in[0];
    const float* gtb  = (const float*)d_in[1];
    const int*   gtc  = (const int*)d_in[2];
    const float* anc  = (const float*)d_in[3];

    char* ws = (char*)d_ws;
    size_t off = 0;
    auto take = [&](size_t bytes) {
        size_t o = off;
        off += (bytes + 255) & ~(size_t)255;
        return o;
    };
    unsigned char*      mask   = (unsigned char*)(ws + take((size_t)B_ * N_));
    int*                cidx   = (int*)(ws + take((size_t)B_ * N_ * 4));
    int*                counts = (int*)(ws + take((size_t)B_ * 2 * 4));
    unsigned long long* bkey   = (unsigned long long*)(ws + take((size_t)B_ * N_ * 8));
    float*              cfeat  = (float*)(ws + take((size_t)B_ * N_ * 8 * 4));
    float*              pobj   = (float*)(ws + take((size_t)NBLK * 4));
    float*              pfg    = (float*)(ws + take((size_t)NBLK * 4 * 4));

    hipMemsetAsync(bkey, 0xFF, (size_t)B_ * N_ * 8, stream);

    const int nblkA = (N_ + 255) / 256; // 132
    dim3 gA(nblkA, B_);
    k_cand<<<gA, 256, 0, stream>>>(gtb, anc, mask);
    k_compact<<<B_, 256, 0, stream>>>(mask, cidx, counts);
    dim3 gS(32, B_);
    k_cfeat<<<gS, 256, 0, stream>>>(pred, cidx, counts, cfeat);
    dim3 gT(G_, B_);
    k_topk<<<gT, 64, 0, stream>>>(pred, gtb, gtc, cidx, counts, cfeat, bkey);
    k_obj<<<NBLK, 256, 0, stream>>>(pred, pobj);
    k_fg<<<NBLK, 256, 0, stream>>>(pred, gtb, gtc, bkey, pfg);
    k_final<<<1, 256, 0, stream>>>(pobj, pfg, NBLK, (float*)d_out);
}

// Round 5
// 44.125 us; speedup vs baseline: 6.3599x; 1.1320x over previous
//
#include <hip/hip_runtime.h>
#include <math.h>

#define B_ 4
#define N_ 33600
#define G_ 100
#define NCLS 80
#define STRIDE 85   // 4 box + 80 cls + 1 obj
#define TK 10
#define NBLK 525    // B_*N_ / 256 exactly

__device__ __forceinline__ float sigmoidf_(float x) {
    return 1.0f / (1.0f + expf(-x));
}
__device__ __forceinline__ float softplusf_(float x) {
    return fmaxf(x, 0.0f) + log1pf(expf(-fabsf(x)));
}
__device__ __forceinline__ float waveRedSum(float v) {
    #pragma unroll
    for (int off = 32; off; off >>= 1) v += __shfl_xor(v, off, 64);
    return v;
}

// ---------------------------------------------------------------- stage 1
// candidate mask + bkey init (replaces the 40us rocclr fill kernel)
__global__ void k_cand(const float* __restrict__ gtb,
                       const float* __restrict__ anc,
                       unsigned char* __restrict__ mask,
                       unsigned long long* __restrict__ bkey)
{
    __shared__ float gcx[G_], gcy[G_];
    const int b = blockIdx.y;
    const int tid = threadIdx.x;
    if (tid < G_) {
        gcx[tid] = gtb[(b * G_ + tid) * 4 + 0];
        gcy[tid] = gtb[(b * G_ + tid) * 4 + 1];
    }
    __syncthreads();
    const int n = blockIdx.x * blockDim.x + tid;
    if (n >= N_) return;
    bkey[(size_t)b * N_ + n] = 0xFFFFFFFFFFFFFFFFull;
    const float2 a = ((const float2*)anc)[n];
    int c = 0;
    #pragma unroll 10
    for (int g = 0; g < G_; ++g) {
        const float dx = a.x - gcx[g], dy = a.y - gcy[g];
        c |= (dx * dx + dy * dy < 6.25f) ? 1 : 0;
    }
    mask[b * N_ + n] = (unsigned char)c;
}

// ---------------------------------------------------------------- stage 2
// ordered compaction, one block per image, 16 mask bytes per thread per chunk
__global__ void k_compact(const unsigned char* __restrict__ mask,
                          int* __restrict__ cidx,
                          int* __restrict__ counts) // [b][0]=n_cand, [b][1]=all_cand
{
    const int b = blockIdx.x;
    const int tid = threadIdx.x;
    const int lane = tid & 63, wid = tid >> 6;
    __shared__ int wsum[4];
    int base = 0;
    const int CH = 4096; // 256 threads * 16 bytes
    for (int chunk = 0; chunk * CH < N_; ++chunk) {
        const int i0 = chunk * CH + tid * 16;
        uint4 v = make_uint4(0, 0, 0, 0);
        if (i0 + 16 <= N_) v = *reinterpret_cast<const uint4*>(mask + (size_t)b * N_ + i0);
        const int cnt = __popc(v.x) + __popc(v.y) + __popc(v.z) + __popc(v.w);
        int incl = cnt;
        #pragma unroll
        for (int off = 1; off < 64; off <<= 1) {
            const int t = __shfl_up(incl, off, 64);
            if (lane >= off) incl += t;
        }
        if (lane == 63) wsum[wid] = incl;
        __syncthreads();
        int wbase = 0;
        for (int w = 0; w < wid; ++w) wbase += wsum[w];
        const int ctot = wsum[0] + wsum[1] + wsum[2] + wsum[3];
        int pos = base + wbase + (incl - cnt);
        if (cnt) {
            const unsigned w4[4] = {v.x, v.y, v.z, v.w};
            #pragma unroll
            for (int j = 0; j < 16; ++j) {
                if ((w4[j >> 2] >> ((j & 3) * 8)) & 1u)
                    cidx[(size_t)b * N_ + pos++] = i0 + j;
            }
        }
        base += ctot;
        __syncthreads();
    }
    if (tid == 0) {
        counts[b * 2 + 0] = base;
        counts[b * 2 + 1] = (base == 0) ? 1 : 0; // fallback: all anchors candidates
    }
}

// ---------------------------------------------------------------- stage 3
// one WAVE per candidate: lanes over classes for spsum; cache per-slot
// features {x1,y1,x2,y2,area,spsum} for k_topk's coalesced consumption.
__global__ void k_cfeat(const float* __restrict__ pred,
                        const int* __restrict__ cidx,
                        const int* __restrict__ counts,
                        float* __restrict__ cfeat) // [B][N][8] slot-indexed
{
    const int b = blockIdx.y;
    const int cnt = counts[b * 2 + 0];
    const int allc = counts[b * 2 + 1];
    if (allc) return; // never-taken fallback handled in k_topk
    const int tid = threadIdx.x;
    const int lane = tid & 63, wid = tid >> 6;
    const int wavesPerImg = gridDim.x * (blockDim.x >> 6);
    const int w0 = blockIdx.x * (blockDim.x >> 6) + wid;
    for (int i = w0; i < cnt; i += wavesPerImg) {
        const int n = cidx[(size_t)b * N_ + i];
        const float* row = pred + (size_t)(b * N_ + n) * STRIDE;
        float s = softplusf_(sigmoidf_(row[4 + lane]));
        if (lane < NCLS - 64) s += softplusf_(sigmoidf_(row[4 + 64 + lane]));
        s = waveRedSum(s);
        if (lane == 0) {
            const float px = row[0], py = row[1], pw = row[2], ph = row[3];
            float* cf = cfeat + (size_t)(b * N_ + i) * 8;
            cf[0] = px - pw * 0.5f;
            cf[1] = py - ph * 0.5f;
            cf[2] = px + pw * 0.5f;
            cf[3] = py + ph * 0.5f;
            cf[4] = pw * ph;
            cf[5] = s;
        }
    }
}

// ---------------------------------------------------------------- stage 4
// one wave per (b,g): iou col-sum -> dyn_k; stable top-10 smallest cost;
// scatter atomicMin((cost_bits<<32)|g) per kept anchor.
__global__ void __launch_bounds__(64)
k_topk(const float* __restrict__ pred,
       const float* __restrict__ gtb,
       const int* __restrict__ gtc,
       const int* __restrict__ cidx,
       const int* __restrict__ counts,
       const float* __restrict__ cfeat,
       unsigned long long* __restrict__ bkey)
{
    const int b = blockIdx.y, g = blockIdx.x;
    const int lane = threadIdx.x;
    const int cnt = counts[b * 2 + 0];
    const int allc = counts[b * 2 + 1];
    const int count = allc ? N_ : cnt;

    const float* gb = gtb + (b * G_ + g) * 4;
    const float gxc = gb[0], gyc = gb[1], gw = gb[2], gh = gb[3];
    const float gx1 = gxc - gw * 0.5f, gy1 = gyc - gh * 0.5f;
    const float gx2 = gxc + gw * 0.5f, gy2 = gyc + gh * 0.5f;
    const float garea = gw * gh;
    const int cls = gtc[b * G_ + g];

    float kcost[TK];
    int   kslot[TK];
    #pragma unroll
    for (int j = 0; j < TK; ++j) { kcost[j] = INFINITY; kslot[j] = 0x7FFFFFFF; }

    float iousum = 0.0f;
    for (int i = lane; i < count; i += 64) {
        float x1, y1, x2, y2, parea, sp;
        int n;
        if (allc) { // never taken in practice (no-candidate fallback)
            n = i;
            const float* pr = pred + (size_t)(b * N_ + n) * STRIDE;
            const float px = pr[0], py = pr[1], pw = pr[2], ph = pr[3];
            x1 = px - pw * 0.5f; y1 = py - ph * 0.5f;
            x2 = px + pw * 0.5f; y2 = py + ph * 0.5f;
            parea = pw * ph;
            float s = 0.0f;
            for (int cc = 0; cc < NCLS; ++cc) s += softplusf_(sigmoidf_(pr[4 + cc]));
            sp = s;
        } else {
            n = cidx[(size_t)b * N_ + i];
            const float* cf = cfeat + (size_t)(b * N_ + i) * 8;
            x1 = cf[0]; y1 = cf[1]; x2 = cf[2]; y2 = cf[3];
            parea = cf[4]; sp = cf[5];
        }
        const float iw = fmaxf(fminf(x2, gx2) - fmaxf(x1, gx1), 0.0f);
        const float ih = fmaxf(fminf(y2, gy2) - fmaxf(y1, gy1), 0.0f);
        const float inter = iw * ih;
        const float uni = parea + garea - inter + 1e-7f;
        const float iou = inter / uni;
        iousum += iou;
        const float sgc = sigmoidf_(pred[(size_t)(b * N_ + n) * STRIDE + 4 + cls]);
        float c = -logf(iou + 1e-8f) + 3.0f * (sp - sgc);
        int   s = i;
        // bubble-insert; slots within a lane strictly increase, so strict <
        // preserves lexicographic (cost, slot) order.
        #pragma unroll
        for (int j = 0; j < TK; ++j) {
            const bool lt = (c < kcost[j]);
            const float tc = kcost[j]; const int ts = kslot[j];
            if (lt) { kcost[j] = c; kslot[j] = s; c = tc; s = ts; }
        }
    }

    // wave-sum of iou column
    #pragma unroll
    for (int off = 32; off; off >>= 1) iousum += __shfl_xor(iousum, off, 64);

    // 10 rounds of wave-wide extract-min on packed (cost_bits, slot) keys.
    // cost > 0 always (cls_cost >= ~54), so float bits are order-preserving.
    unsigned long long win[TK];
    #pragma unroll
    for (int r = 0; r < TK; ++r) {
        const unsigned long long mykey =
            ((unsigned long long)__float_as_uint(kcost[0]) << 32) | (unsigned)kslot[0];
        unsigned long long k2 = mykey;
        #pragma unroll
        for (int off = 32; off; off >>= 1) {
            const unsigned long long o = __shfl_xor(k2, off, 64);
            k2 = (o < k2) ? o : k2;
        }
        win[r] = k2;
        if (mykey == k2) { // unique (slot unique per lane); pop my head
            #pragma unroll
            for (int j = 0; j < TK - 1; ++j) { kcost[j] = kcost[j + 1]; kslot[j] = kslot[j + 1]; }
            kcost[TK - 1] = INFINITY; kslot[TK - 1] = 0x7FFFFFFF;
        }
    }

    const int kmax = (count < TK) ? count : TK;
    int dk = (int)floorf(iousum);
    if (dk < 1) dk = 1;
    if (dk > kmax) dk = kmax;

    if (lane == 0) {
        #pragma unroll
        for (int r = 0; r < TK; ++r) {
            if (r < dk) {
                const unsigned slot = (unsigned)(win[r] & 0xFFFFFFFFull);
                const int n = allc ? (int)slot : cidx[(size_t)b * N_ + (int)slot];
                const unsigned cbits = (unsigned)(win[r] >> 32);
                const unsigned long long key =
                    ((unsigned long long)cbits << 32) | (unsigned)g;
                atomicMin(&bkey[(size_t)b * N_ + n], key);
            }
        }
    }
}

// ---------------------------------------------------------------- stage 5
// merged obj + fg: per-thread softplus(obj logit); ballot-cooperative fg
// terms (whole wave does focal over classes; lane 0 does CIoU).
// partials: 8 floats per block = {so, posum, box, cls}, {npos,0,0,0}
__global__ void k_objfg(const float* __restrict__ pred,
                        const float* __restrict__ gtb,
                        const int* __restrict__ gtc,
                        const unsigned long long* __restrict__ bkey,
                        float* __restrict__ part)
{
    const int tid = threadIdx.x;
    const unsigned i = blockIdx.x * blockDim.x + tid; // anchor flat id, < B_*N_
    const int lane = tid & 63, wid = tid >> 6;
    const unsigned long long key = bkey[i];
    const bool fg = (key != 0xFFFFFFFFFFFFFFFFull);
    float so = softplusf_(pred[(size_t)i * STRIDE + (STRIDE - 1)]);
    float posum = 0.0f, box = 0.0f, clsacc = 0.0f, npos = 0.0f;

    unsigned long long m = __ballot(fg);
    while (m) {
        const int src = (int)__ffsll((unsigned long long)m) - 1;
        m &= (m - 1);
        const unsigned ai = (unsigned)__shfl((int)i, src, 64);
        const int mg = __shfl((int)(unsigned)(key & 0xFFFFFFFFull), src, 64);
        const int b = (int)(ai / (unsigned)N_);
        const float* pr = pred + (size_t)ai * STRIDE;
        const int cg = gtc[b * G_ + mg];
        // focal term: lane handles class `lane` (and `64+lane` for lane<16)
        {
            const float x = pr[4 + lane];
            const float t = (lane == cg) ? 1.0f : 0.0f;
            const float bce = softplusf_(x) - x * t;
            const float p = sigmoidf_(x);
            const float pt = t * p + (1.0f - t) * (1.0f - p);
            const float om = 1.0f - pt;
            clsacc += 0.25f * om * om * bce;
        }
        if (lane < NCLS - 64) {
            const float x = pr[4 + 64 + lane];
            const float t = ((64 + lane) == cg) ? 1.0f : 0.0f;
            const float bce = softplusf_(x) - x * t;
            const float p = sigmoidf_(x);
            const float pt = t * p + (1.0f - t) * (1.0f - p);
            const float om = 1.0f - pt;
            clsacc += 0.25f * om * om * bce;
        }
        if (lane == 0) {
            npos += 1.0f;
            posum += pr[STRIDE - 1];
            const float* gb = gtb + (b * G_ + mg) * 4;
            const float px = pr[0], py = pr[1], pw = pr[2], ph = pr[3];
            const float gx = gb[0], gy = gb[1], gw = gb[2], gh = gb[3];
            const float x11 = px - pw * 0.5f, y11 = py - ph * 0.5f;
            const float x12 = px + pw * 0.5f, y12 = py + ph * 0.5f;
            const float x21 = gx - gw * 0.5f, y21 = gy - gh * 0.5f;
            const float x22 = gx + gw * 0.5f, y22 = gy + gh * 0.5f;
            const float iw = fmaxf(fminf(x12, x22) - fmaxf(x11, x21), 0.0f);
            const float ih = fmaxf(fminf(y12, y22) - fmaxf(y11, y21), 0.0f);
            const float inter = iw * ih;
            const float uni = pw * ph + gw * gh - inter + 1e-7f;
            const float iou = inter / uni;
            const float cw = fmaxf(x12, x22) - fminf(x11, x21);
            const float chh = fmaxf(y12, y22) - fminf(y11, y21);
            const float c2 = cw * cw + chh * chh + 1e-7f;
            const float ddx = x11 + x12 - x21 - x22;
            const float ddy = y11 + y12 - y21 - y22;
            const float rho2 = (ddx * ddx + ddy * ddy) * 0.25f;
            const float dv = atanf(gw / (gh + 1e-7f)) - atanf(pw / (ph + 1e-7f));
            const float v = (float)(4.0 / (M_PI * M_PI)) * dv * dv;
            const float alpha = v / (v - iou + 1.0f + 1e-7f);
            const float ciou = iou - (rho2 / c2 + v * alpha);
            box += 1.0f - ciou;
        }
    }

    so = waveRedSum(so);
    posum = waveRedSum(posum);
    box = waveRedSum(box);
    clsacc = waveRedSum(clsacc);
    npos = waveRedSum(npos);
    __shared__ float ws[4][5];
    if (lane == 0) {
        ws[wid][0] = so; ws[wid][1] = posum; ws[wid][2] = box;
        ws[wid][3] = clsacc; ws[wid][4] = npos;
    }
    __syncthreads();
    if (tid == 0) {
        float r[5];
        #pragma unroll
        for (int k = 0; k < 5; ++k)
            r[k] = ws[0][k] + ws[1][k] + ws[2][k] + ws[3][k];
        float4* p = (float4*)part;
        p[blockIdx.x * 2 + 0] = make_float4(r[0], r[1], r[2], r[3]);
        p[blockIdx.x * 2 + 1] = make_float4(r[4], 0.0f, 0.0f, 0.0f);
    }
}

// ---------------------------------------------------------------- stage 6
__global__ void k_final(const float* __restrict__ part, int nblocks,
                        float* __restrict__ out)
{
    const int tid = threadIdx.x;
    float so = 0, sp = 0, sb = 0, sc = 0, sn = 0;
    for (int i = tid; i < nblocks; i += 256) {
        const float4 a = ((const float4*)part)[i * 2 + 0];
        const float4 b = ((const float4*)part)[i * 2 + 1];
        so += a.x; sp += a.y; sb += a.z; sc += a.w; sn += b.x;
    }
    __shared__ float red[256];
    float in5[5] = {so, sp, sb, sc, sn};
    float res[5];
    #pragma unroll
    for (int k = 0; k < 5; ++k) {
        red[tid] = in5[k];
        __syncthreads();
        for (int s = 128; s > 0; s >>= 1) {
            if (tid < s) red[tid] += red[tid + s];
            __syncthreads();
        }
        res[k] = red[0];
        __syncthreads();
    }
    if (tid == 0) {
        const float obj_sum = res[0] - res[1]; // sum softplus(po) - sum_{fg} po
        const float n_pos = fmaxf(res[4], 1.0f);
        const float total = 7.5f * res[2] / n_pos
                          + 0.5f * res[3] / n_pos
                          + obj_sum / (float)N_;
        out[0] = total;
    }
}

extern "C" void kernel_launch(void* const* d_in, const int* in_sizes, int n_in,
                              void* d_out, int out_size, void* d_ws, size_t ws_size,
                              hipStream_t stream)
{
    const float* pred = (const float*)d_in[0];
    const float* gtb  = (const float*)d_in[1];
    const int*   gtc  = (const int*)d_in[2];
    const float* anc  = (const float*)d_in[3];

    char* ws = (char*)d_ws;
    size_t off = 0;
    auto take = [&](size_t bytes) {
        size_t o = off;
        off += (bytes + 255) & ~(size_t)255;
        return o;
    };
    unsigned char*      mask   = (unsigned char*)(ws + take((size_t)B_ * N_));
    int*                cidx   = (int*)(ws + take((size_t)B_ * N_ * 4));
    int*                counts = (int*)(ws + take((size_t)B_ * 2 * 4));
    unsigned long long* bkey   = (unsigned long long*)(ws + take((size_t)B_ * N_ * 8));
    float*              cfeat  = (float*)(ws + take((size_t)B_ * N_ * 8 * 4));
    float*              part   = (float*)(ws + take((size_t)NBLK * 8 * 4));

    const int nblkA = (N_ + 255) / 256; // 132
    dim3 gA(nblkA, B_);
    k_cand<<<gA, 256, 0, stream>>>(gtb, anc, mask, bkey);
    k_compact<<<B_, 256, 0, stream>>>(mask, cidx, counts);
    dim3 gS(32, B_);
    k_cfeat<<<gS, 256, 0, stream>>>(pred, cidx, counts, cfeat);
    dim3 gT(G_, B_);
    k_topk<<<gT, 64, 0, stream>>>(pred, gtb, gtc, cidx, counts, cfeat, bkey);
    k_objfg<<<NBLK, 256, 0, stream>>>(pred, gtb, gtc, bkey, part);
    k_final<<<1, 256, 0, stream>>>(part, NBLK, (float*)d_out);
}